// Round 1
// baseline (274.531 us; speedup 1.0000x reference)
//
#include <hip/hip_runtime.h>

#define LN_EPS 1e-5f

typedef float vfloat4 __attribute__((ext_vector_type(4)));

// Kernel 1: per-batch  o[b] = (LN(act[b]) @ vw + vb) @ ow + ob
// 32 blocks (one per batch), 1024 threads: 4 reduction slices x 256 columns.
__global__ __launch_bounds__(1024) void compute_o_kernel(
    const float* __restrict__ act,   // [32,256]
    const float* __restrict__ ln_w,  // [256]
    const float* __restrict__ ln_b,  // [256]
    const float* __restrict__ vw,    // [256,256] row-major [a][c]
    const float* __restrict__ vb,    // [256]
    const float* __restrict__ ow,    // [256,256] row-major [j][c]
    const float* __restrict__ ob,    // [256]
    float* __restrict__ o)           // [32,256]
{
    const int b = blockIdx.x;
    const int t = threadIdx.x;   // 0..1023
    const int c = t & 255;       // output column
    const int s = t >> 8;        // reduction slice 0..3

    __shared__ float sa[256];    // act row, then normalized act
    __shared__ float sv[256];    // v vector
    __shared__ float red[1024];  // cross-slice partials
    __shared__ float stats[2];   // mu, inv_sigma

    if (t < 256) sa[t] = act[b * 256 + t];
    __syncthreads();

    // LayerNorm stats: sum & sumsq over 256 elems via wave shuffles (4 waves)
    if (t < 256) {
        float x = sa[t];
        float sum = x, sq = x * x;
        #pragma unroll
        for (int off = 32; off > 0; off >>= 1) {
            sum += __shfl_xor(sum, off, 64);
            sq  += __shfl_xor(sq,  off, 64);
        }
        if ((t & 63) == 0) { red[t >> 6] = sum; red[4 + (t >> 6)] = sq; }
    }
    __syncthreads();
    if (t == 0) {
        float sum = red[0] + red[1] + red[2] + red[3];
        float sq  = red[4] + red[5] + red[6] + red[7];
        float mu  = sum * (1.0f / 256.0f);
        float var = sq * (1.0f / 256.0f) - mu * mu;
        stats[0] = mu;
        stats[1] = rsqrtf(var + LN_EPS);
    }
    __syncthreads();
    if (t < 256) {
        sa[t] = (sa[t] - stats[0]) * stats[1] * ln_w[t] + ln_b[t];
    }
    __syncthreads();

    // GEMV1: v[c] = vb[c] + sum_a an[a] * vw[a][c], split over 4 slices
    const int a0 = s * 64;
    float acc = 0.f;
    #pragma unroll 8
    for (int i = 0; i < 64; ++i) {
        const int a = a0 + i;
        acc += sa[a] * vw[a * 256 + c];   // sa[a]: LDS broadcast; vw: coalesced
    }
    red[t] = acc;
    __syncthreads();
    if (t < 256) {
        sv[t] = vb[t] + red[t] + red[t + 256] + red[t + 512] + red[t + 768];
    }
    __syncthreads();

    // GEMV2: o[c] = ob[c] + sum_j v[j] * ow[j][c]
    float acc2 = 0.f;
    #pragma unroll 8
    for (int i = 0; i < 64; ++i) {
        const int j = a0 + i;
        acc2 += sv[j] * ow[j * 256 + c];
    }
    red[t] = acc2;
    __syncthreads();
    if (t < 256) {
        o[b * 256 + t] = ob[t] + red[t] + red[t + 256] + red[t + 512] + red[t + 768];
    }
}

// Kernel 2: out[b,c,:,:] = img[b,c,:,:] + o[b,c]
// 2048 blocks x 256 threads; each block handles 4 consecutive (b,c) planes
// (4 x 16 KiB). All 16 float4 loads are issued before any store so each
// thread keeps 16 loads in flight (256 B/thread). Cached loads (drop the
// nontemporal hint on the read stream), nontemporal stores (write-once).
__global__ __launch_bounds__(256) void residual_add_kernel(
    const float* __restrict__ img,
    const float* __restrict__ o,
    float* __restrict__ out)
{
    const int blk = blockIdx.x;       // 0..2047
    const int t   = threadIdx.x;      // 0..255
    const int bc0 = blk << 2;         // first of 4 planes

    const float o0 = o[bc0 + 0];
    const float o1 = o[bc0 + 1];
    const float o2 = o[bc0 + 2];
    const float o3 = o[bc0 + 3];

    const vfloat4* __restrict__ img4 = (const vfloat4*)(img + (size_t)bc0 * 4096);
    vfloat4* __restrict__ out4       = (vfloat4*)(out + (size_t)bc0 * 4096);

    // plane p occupies float4 indices [p*1024, (p+1)*1024) within this block's span
    vfloat4 x[16];
    #pragma unroll
    for (int p = 0; p < 4; ++p) {
        #pragma unroll
        for (int i = 0; i < 4; ++i) {
            x[p * 4 + i] = img4[p * 1024 + i * 256 + t];
        }
    }

    x[0]  += o0; x[1]  += o0; x[2]  += o0; x[3]  += o0;
    x[4]  += o1; x[5]  += o1; x[6]  += o1; x[7]  += o1;
    x[8]  += o2; x[9]  += o2; x[10] += o2; x[11] += o2;
    x[12] += o3; x[13] += o3; x[14] += o3; x[15] += o3;

    #pragma unroll
    for (int p = 0; p < 4; ++p) {
        #pragma unroll
        for (int i = 0; i < 4; ++i) {
            __builtin_nontemporal_store(x[p * 4 + i], out4 + p * 1024 + i * 256 + t);
        }
    }
}

extern "C" void kernel_launch(void* const* d_in, const int* in_sizes, int n_in,
                              void* d_out, int out_size, void* d_ws, size_t ws_size,
                              hipStream_t stream) {
    // Input order: img, act, gn_w, gn_b, ln_w, ln_b, qw, qb, kw, kb, vw, vb, ow, ob
    const float* img  = (const float*)d_in[0];
    const float* act  = (const float*)d_in[1];
    const float* ln_w = (const float*)d_in[4];
    const float* ln_b = (const float*)d_in[5];
    const float* vw   = (const float*)d_in[10];
    const float* vb   = (const float*)d_in[11];
    const float* ow   = (const float*)d_in[12];
    const float* ob   = (const float*)d_in[13];
    float* out = (float*)d_out;
    float* o   = (float*)d_ws;   // 32*256 floats = 32 KB scratch

    compute_o_kernel<<<32, 1024, 0, stream>>>(act, ln_w, ln_b, vw, vb, ow, ob, o);
    residual_add_kernel<<<2048, 256, 0, stream>>>(img, o, out);
}

// Round 2
// 266.087 us; speedup vs baseline: 1.0317x; 1.0317x over previous
//
#include <hip/hip_runtime.h>

#define LN_EPS 1e-5f

typedef float vfloat4 __attribute__((ext_vector_type(4)));

// Kernel 1: per-batch  o[b] = (LN(act[b]) @ vw + vb) @ ow + ob
// 32 blocks (one per batch), 1024 threads: 4 reduction slices x 256 columns.
__global__ __launch_bounds__(1024) void compute_o_kernel(
    const float* __restrict__ act,   // [32,256]
    const float* __restrict__ ln_w,  // [256]
    const float* __restrict__ ln_b,  // [256]
    const float* __restrict__ vw,    // [256,256] row-major [a][c]
    const float* __restrict__ vb,    // [256]
    const float* __restrict__ ow,    // [256,256] row-major [j][c]
    const float* __restrict__ ob,    // [256]
    float* __restrict__ o)           // [32,256]
{
    const int b = blockIdx.x;
    const int t = threadIdx.x;   // 0..1023
    const int c = t & 255;       // output column
    const int s = t >> 8;        // reduction slice 0..3

    __shared__ float sa[256];    // act row, then normalized act
    __shared__ float sv[256];    // v vector
    __shared__ float red[1024];  // cross-slice partials
    __shared__ float stats[2];   // mu, inv_sigma

    if (t < 256) sa[t] = act[b * 256 + t];
    __syncthreads();

    // LayerNorm stats: sum & sumsq over 256 elems via wave shuffles (4 waves)
    if (t < 256) {
        float x = sa[t];
        float sum = x, sq = x * x;
        #pragma unroll
        for (int off = 32; off > 0; off >>= 1) {
            sum += __shfl_xor(sum, off, 64);
            sq  += __shfl_xor(sq,  off, 64);
        }
        if ((t & 63) == 0) { red[t >> 6] = sum; red[4 + (t >> 6)] = sq; }
    }
    __syncthreads();
    if (t == 0) {
        float sum = red[0] + red[1] + red[2] + red[3];
        float sq  = red[4] + red[5] + red[6] + red[7];
        float mu  = sum * (1.0f / 256.0f);
        float var = sq * (1.0f / 256.0f) - mu * mu;
        stats[0] = mu;
        stats[1] = rsqrtf(var + LN_EPS);
    }
    __syncthreads();
    if (t < 256) {
        sa[t] = (sa[t] - stats[0]) * stats[1] * ln_w[t] + ln_b[t];
    }
    __syncthreads();

    // GEMV1: v[c] = vb[c] + sum_a an[a] * vw[a][c], split over 4 slices
    const int a0 = s * 64;
    float acc = 0.f;
    #pragma unroll 8
    for (int i = 0; i < 64; ++i) {
        const int a = a0 + i;
        acc += sa[a] * vw[a * 256 + c];   // sa[a]: LDS broadcast; vw: coalesced
    }
    red[t] = acc;
    __syncthreads();
    if (t < 256) {
        sv[t] = vb[t] + red[t] + red[t + 256] + red[t + 512] + red[t + 768];
    }
    __syncthreads();

    // GEMV2: o[c] = ob[c] + sum_j v[j] * ow[j][c]
    float acc2 = 0.f;
    #pragma unroll 8
    for (int i = 0; i < 64; ++i) {
        const int j = a0 + i;
        acc2 += sv[j] * ow[j * 256 + c];
    }
    red[t] = acc2;
    __syncthreads();
    if (t < 256) {
        o[b * 256 + t] = ob[t] + red[t] + red[t + 256] + red[t + 512] + red[t + 768];
    }
}

// Kernel 2: out[b,c,:,:] = img[b,c,:,:] + o[b,c]
// One block per (b,c) plane of 64*64 = 4096 floats (16 KiB).
// 8192 blocks x 256 threads -> 8 blocks/CU resident, 32 waves/CU (max TLP).
// CACHED loads (L3 serves ~half of img for free after the poison fill;
// round-1 counters: FETCH 65.7 MB vs 134 MB logical) issued as a batch of 4
// before any store; NONTEMPORAL stores (write-once stream, keep it out of L3).
__global__ __launch_bounds__(256) void residual_add_kernel(
    const float* __restrict__ img,
    const float* __restrict__ o,
    float* __restrict__ out)
{
    const int bc = blockIdx.x;        // 0..8191  (= b*256 + c)
    const int t  = threadIdx.x;
    const float ov = o[bc];           // block-uniform -> scalar load
    const vfloat4* __restrict__ img4 = (const vfloat4*)(img + (size_t)bc * 4096);
    vfloat4* __restrict__ out4       = (vfloat4*)(out + (size_t)bc * 4096);

    vfloat4 x0 = img4[t];
    vfloat4 x1 = img4[t + 256];
    vfloat4 x2 = img4[t + 512];
    vfloat4 x3 = img4[t + 768];

    x0 += ov; x1 += ov; x2 += ov; x3 += ov;

    __builtin_nontemporal_store(x0, out4 + t);
    __builtin_nontemporal_store(x1, out4 + t + 256);
    __builtin_nontemporal_store(x2, out4 + t + 512);
    __builtin_nontemporal_store(x3, out4 + t + 768);
}

extern "C" void kernel_launch(void* const* d_in, const int* in_sizes, int n_in,
                              void* d_out, int out_size, void* d_ws, size_t ws_size,
                              hipStream_t stream) {
    // Input order: img, act, gn_w, gn_b, ln_w, ln_b, qw, qb, kw, kb, vw, vb, ow, ob
    const float* img  = (const float*)d_in[0];
    const float* act  = (const float*)d_in[1];
    const float* ln_w = (const float*)d_in[4];
    const float* ln_b = (const float*)d_in[5];
    const float* vw   = (const float*)d_in[10];
    const float* vb   = (const float*)d_in[11];
    const float* ow   = (const float*)d_in[12];
    const float* ob   = (const float*)d_in[13];
    float* out = (float*)d_out;
    float* o   = (float*)d_ws;   // 32*256 floats = 32 KB scratch

    compute_o_kernel<<<32, 1024, 0, stream>>>(act, ln_w, ln_b, vw, vb, ow, ob, o);
    residual_add_kernel<<<8192, 256, 0, stream>>>(img, o, out);
}

// Round 3
// 264.649 us; speedup vs baseline: 1.0373x; 1.0054x over previous
//
#include <hip/hip_runtime.h>

#define LN_EPS 1e-5f

typedef float vfloat4 __attribute__((ext_vector_type(4)));

// Kernel 1: per-batch  o[b] = (LN(act[b]) @ vw + vb) @ ow + ob
// 32 blocks (one per batch), 1024 threads: 4 reduction slices x 256 columns.
__global__ __launch_bounds__(1024) void compute_o_kernel(
    const float* __restrict__ act,   // [32,256]
    const float* __restrict__ ln_w,  // [256]
    const float* __restrict__ ln_b,  // [256]
    const float* __restrict__ vw,    // [256,256] row-major [a][c]
    const float* __restrict__ vb,    // [256]
    const float* __restrict__ ow,    // [256,256] row-major [j][c]
    const float* __restrict__ ob,    // [256]
    float* __restrict__ o)           // [32,256]
{
    const int b = blockIdx.x;
    const int t = threadIdx.x;   // 0..1023
    const int c = t & 255;       // output column
    const int s = t >> 8;        // reduction slice 0..3

    __shared__ float sa[256];    // act row, then normalized act
    __shared__ float sv[256];    // v vector
    __shared__ float red[1024];  // cross-slice partials
    __shared__ float stats[2];   // mu, inv_sigma

    if (t < 256) sa[t] = act[b * 256 + t];
    __syncthreads();

    // LayerNorm stats: sum & sumsq over 256 elems via wave shuffles (4 waves)
    if (t < 256) {
        float x = sa[t];
        float sum = x, sq = x * x;
        #pragma unroll
        for (int off = 32; off > 0; off >>= 1) {
            sum += __shfl_xor(sum, off, 64);
            sq  += __shfl_xor(sq,  off, 64);
        }
        if ((t & 63) == 0) { red[t >> 6] = sum; red[4 + (t >> 6)] = sq; }
    }
    __syncthreads();
    if (t == 0) {
        float sum = red[0] + red[1] + red[2] + red[3];
        float sq  = red[4] + red[5] + red[6] + red[7];
        float mu  = sum * (1.0f / 256.0f);
        float var = sq * (1.0f / 256.0f) - mu * mu;
        stats[0] = mu;
        stats[1] = rsqrtf(var + LN_EPS);
    }
    __syncthreads();
    if (t < 256) {
        sa[t] = (sa[t] - stats[0]) * stats[1] * ln_w[t] + ln_b[t];
    }
    __syncthreads();

    // GEMV1: v[c] = vb[c] + sum_a an[a] * vw[a][c], split over 4 slices
    const int a0 = s * 64;
    float acc = 0.f;
    #pragma unroll 8
    for (int i = 0; i < 64; ++i) {
        const int a = a0 + i;
        acc += sa[a] * vw[a * 256 + c];   // sa[a]: LDS broadcast; vw: coalesced
    }
    red[t] = acc;
    __syncthreads();
    if (t < 256) {
        sv[t] = vb[t] + red[t] + red[t + 256] + red[t + 512] + red[t + 768];
    }
    __syncthreads();

    // GEMV2: o[c] = ob[c] + sum_j v[j] * ow[j][c]
    float acc2 = 0.f;
    #pragma unroll 8
    for (int i = 0; i < 64; ++i) {
        const int j = a0 + i;
        acc2 += sv[j] * ow[j * 256 + c];
    }
    red[t] = acc2;
    __syncthreads();
    if (t < 256) {
        o[b * 256 + t] = ob[t] + red[t] + red[t + 256] + red[t + 512] + red[t + 768];
    }
}

// Kernel 2: out[b,c,:,:] = img[b,c,:,:] + o[b,c]
// DISCRIMINATING EXPERIMENT: fully-cached policy (plain loads AND plain
// stores, no nontemporal hints) — the one untested cell of the policy
// matrix. Matches the m13 float4-copy microbenchmark that achieved
// 6.29 TB/s. Structure identical to R0 (the best so far): one block per
// 16 KiB (b,c) plane, 8192 blocks x 256 threads, 4 float4 per thread.
//   - If NT hints were capping throughput: residual ~43-50 us, total ~235.
//   - If the dirty-L3/poison-writeback theory is right: total >= 258,
//     and we revert to the NT-everywhere R0 kernel as the ceiling.
__global__ __launch_bounds__(256) void residual_add_kernel(
    const float* __restrict__ img,
    const float* __restrict__ o,
    float* __restrict__ out)
{
    const int bc = blockIdx.x;        // 0..8191  (= b*256 + c)
    const int t  = threadIdx.x;
    const float ov = o[bc];           // block-uniform -> scalar load
    const vfloat4* __restrict__ img4 = (const vfloat4*)(img + (size_t)bc * 4096);
    vfloat4* __restrict__ out4       = (vfloat4*)(out + (size_t)bc * 4096);
    #pragma unroll
    for (int i = 0; i < 4; ++i) {
        vfloat4 x = img4[t + 256 * i];
        x += ov;
        out4[t + 256 * i] = x;
    }
}

extern "C" void kernel_launch(void* const* d_in, const int* in_sizes, int n_in,
                              void* d_out, int out_size, void* d_ws, size_t ws_size,
                              hipStream_t stream) {
    // Input order: img, act, gn_w, gn_b, ln_w, ln_b, qw, qb, kw, kb, vw, vb, ow, ob
    const float* img  = (const float*)d_in[0];
    const float* act  = (const float*)d_in[1];
    const float* ln_w = (const float*)d_in[4];
    const float* ln_b = (const float*)d_in[5];
    const float* vw   = (const float*)d_in[10];
    const float* vb   = (const float*)d_in[11];
    const float* ow   = (const float*)d_in[12];
    const float* ob   = (const float*)d_in[13];
    float* out = (float*)d_out;
    float* o   = (float*)d_ws;   // 32*256 floats = 32 KB scratch

    compute_o_kernel<<<32, 1024, 0, stream>>>(act, ln_w, ln_b, vw, vb, ow, ob, o);
    residual_add_kernel<<<8192, 256, 0, stream>>>(img, o, out);
}

// Round 4
// 257.097 us; speedup vs baseline: 1.0678x; 1.0294x over previous
//
#include <hip/hip_runtime.h>

#define LN_EPS 1e-5f

typedef float vfloat4 __attribute__((ext_vector_type(4)));

// Kernel 1: per-batch  o[b] = (LN(act[b]) @ vw + vb) @ ow + ob
// 32 blocks (one per batch), 1024 threads: 4 reduction slices x 256 columns.
__global__ __launch_bounds__(1024) void compute_o_kernel(
    const float* __restrict__ act,   // [32,256]
    const float* __restrict__ ln_w,  // [256]
    const float* __restrict__ ln_b,  // [256]
    const float* __restrict__ vw,    // [256,256] row-major [a][c]
    const float* __restrict__ vb,    // [256]
    const float* __restrict__ ow,    // [256,256] row-major [j][c]
    const float* __restrict__ ob,    // [256]
    float* __restrict__ o)           // [32,256]
{
    const int b = blockIdx.x;
    const int t = threadIdx.x;   // 0..1023
    const int c = t & 255;       // output column
    const int s = t >> 8;        // reduction slice 0..3

    __shared__ float sa[256];    // act row, then normalized act
    __shared__ float sv[256];    // v vector
    __shared__ float red[1024];  // cross-slice partials
    __shared__ float stats[2];   // mu, inv_sigma

    if (t < 256) sa[t] = act[b * 256 + t];
    __syncthreads();

    // LayerNorm stats: sum & sumsq over 256 elems via wave shuffles (4 waves)
    if (t < 256) {
        float x = sa[t];
        float sum = x, sq = x * x;
        #pragma unroll
        for (int off = 32; off > 0; off >>= 1) {
            sum += __shfl_xor(sum, off, 64);
            sq  += __shfl_xor(sq,  off, 64);
        }
        if ((t & 63) == 0) { red[t >> 6] = sum; red[4 + (t >> 6)] = sq; }
    }
    __syncthreads();
    if (t == 0) {
        float sum = red[0] + red[1] + red[2] + red[3];
        float sq  = red[4] + red[5] + red[6] + red[7];
        float mu  = sum * (1.0f / 256.0f);
        float var = sq * (1.0f / 256.0f) - mu * mu;
        stats[0] = mu;
        stats[1] = rsqrtf(var + LN_EPS);
    }
    __syncthreads();
    if (t < 256) {
        sa[t] = (sa[t] - stats[0]) * stats[1] * ln_w[t] + ln_b[t];
    }
    __syncthreads();

    // GEMV1: v[c] = vb[c] + sum_a an[a] * vw[a][c], split over 4 slices
    const int a0 = s * 64;
    float acc = 0.f;
    #pragma unroll 8
    for (int i = 0; i < 64; ++i) {
        const int a = a0 + i;
        acc += sa[a] * vw[a * 256 + c];   // sa[a]: LDS broadcast; vw: coalesced
    }
    red[t] = acc;
    __syncthreads();
    if (t < 256) {
        sv[t] = vb[t] + red[t] + red[t + 256] + red[t + 512] + red[t + 768];
    }
    __syncthreads();

    // GEMV2: o[c] = ob[c] + sum_j v[j] * ow[j][c]
    float acc2 = 0.f;
    #pragma unroll 8
    for (int i = 0; i < 64; ++i) {
        const int j = a0 + i;
        acc2 += sv[j] * ow[j * 256 + c];
    }
    red[t] = acc2;
    __syncthreads();
    if (t < 256) {
        o[b * 256 + t] = ob[t] + red[t] + red[t + 256] + red[t + 512] + red[t + 768];
    }
}

// Kernel 2: out[b,c,:,:] = img[b,c,:,:] + o[b,c]
// FINAL POLICY CELL: NT loads + CACHED stores.
// Measured matrix (same 8192x256 structure): NT/NT=255.0, C/NT=266.1,
// C/C=264.6. NT loads avoid read-allocation into the poison-dirtied L3
// (~10 us win); cached stores displace already-dirty poison lines for
// free and were +1.5 us vs NT stores in the cached-load pair.
// One block per 16 KiB (b,c) plane, 8192 blocks x 256 threads,
// 4 float4 loads in flight per thread.
__global__ __launch_bounds__(256) void residual_add_kernel(
    const float* __restrict__ img,
    const float* __restrict__ o,
    float* __restrict__ out)
{
    const int bc = blockIdx.x;        // 0..8191  (= b*256 + c)
    const int t  = threadIdx.x;
    const float ov = o[bc];           // block-uniform -> scalar load
    const vfloat4* __restrict__ img4 = (const vfloat4*)(img + (size_t)bc * 4096);
    vfloat4* __restrict__ out4       = (vfloat4*)(out + (size_t)bc * 4096);

    vfloat4 x0 = __builtin_nontemporal_load(img4 + t);
    vfloat4 x1 = __builtin_nontemporal_load(img4 + t + 256);
    vfloat4 x2 = __builtin_nontemporal_load(img4 + t + 512);
    vfloat4 x3 = __builtin_nontemporal_load(img4 + t + 768);

    x0 += ov; x1 += ov; x2 += ov; x3 += ov;

    out4[t]       = x0;
    out4[t + 256] = x1;
    out4[t + 512] = x2;
    out4[t + 768] = x3;
}

extern "C" void kernel_launch(void* const* d_in, const int* in_sizes, int n_in,
                              void* d_out, int out_size, void* d_ws, size_t ws_size,
                              hipStream_t stream) {
    // Input order: img, act, gn_w, gn_b, ln_w, ln_b, qw, qb, kw, kb, vw, vb, ow, ob
    const float* img  = (const float*)d_in[0];
    const float* act  = (const float*)d_in[1];
    const float* ln_w = (const float*)d_in[4];
    const float* ln_b = (const float*)d_in[5];
    const float* vw   = (const float*)d_in[10];
    const float* vb   = (const float*)d_in[11];
    const float* ow   = (const float*)d_in[12];
    const float* ob   = (const float*)d_in[13];
    float* out = (float*)d_out;
    float* o   = (float*)d_ws;   // 32*256 floats = 32 KB scratch

    compute_o_kernel<<<32, 1024, 0, stream>>>(act, ln_w, ln_b, vw, vb, ow, ob, o);
    residual_add_kernel<<<8192, 256, 0, stream>>>(img, o, out);
}

// Round 5
// 255.964 us; speedup vs baseline: 1.0725x; 1.0044x over previous
//
#include <hip/hip_runtime.h>

#define LN_EPS 1e-5f

typedef float vfloat4 __attribute__((ext_vector_type(4)));

// Kernel 1: o[b] = (LN(act[b]) @ vw + vb) @ ow + ob
// 256 blocks x 256 threads: block = (batch b, column-group g of 32 cols).
// Each block redundantly computes LN + full GEMV1 (thread j owns v[j];
// vw rows are shared by ALL blocks -> L2-multicast, ~2MB cold HBM total),
// then GEMV2 for its 32 columns. vs the old 32-block version: all 256 CUs
// active, 16-deep load pipelining, L2-latency chains instead of HBM.
__global__ __launch_bounds__(256) void compute_o_kernel(
    const float* __restrict__ act,   // [32,256]
    const float* __restrict__ ln_w,  // [256]
    const float* __restrict__ ln_b,  // [256]
    const float* __restrict__ vw,    // [256,256] row-major [a][c]
    const float* __restrict__ vb,    // [256]
    const float* __restrict__ ow,    // [256,256] row-major [j][c]
    const float* __restrict__ ob,    // [256]
    float* __restrict__ o)           // [32,256]
{
    const int b = blockIdx.x >> 3;   // batch 0..31
    const int g = blockIdx.x & 7;    // column group 0..7 (32 cols each)
    const int t = threadIdx.x;       // 0..255

    __shared__ float sa[256];        // act row -> normalized act
    __shared__ float sv[256];        // v vector
    __shared__ float red[256];       // partials
    __shared__ float stats[2];       // mu, inv_sigma

    sa[t] = act[b * 256 + t];
    __syncthreads();

    // LayerNorm stats over 256 elems: wave shuffle + 4-wave LDS combine
    {
        float x = sa[t];
        float sum = x, sq = x * x;
        #pragma unroll
        for (int off = 32; off > 0; off >>= 1) {
            sum += __shfl_xor(sum, off, 64);
            sq  += __shfl_xor(sq,  off, 64);
        }
        if ((t & 63) == 0) { red[t >> 6] = sum; red[4 + (t >> 6)] = sq; }
    }
    __syncthreads();
    if (t == 0) {
        float sum = red[0] + red[1] + red[2] + red[3];
        float sq  = red[4] + red[5] + red[6] + red[7];
        float mu  = sum * (1.0f / 256.0f);
        float var = sq * (1.0f / 256.0f) - mu * mu;
        stats[0] = mu;
        stats[1] = rsqrtf(var + LN_EPS);
    }
    __syncthreads();
    sa[t] = (sa[t] - stats[0]) * stats[1] * ln_w[t] + ln_b[t];
    __syncthreads();

    // GEMV1: thread t computes v[t] = vb[t] + sum_a an[a] * vw[a][t].
    // sa[a] is an LDS broadcast; vw row load is 1KB coalesced, L2-multicast
    // across all 256 blocks. unroll 16 -> 16 loads in flight.
    {
        float acc = vb[t];
        #pragma unroll 16
        for (int a = 0; a < 256; ++a) {
            acc += sa[a] * vw[a * 256 + t];
        }
        sv[t] = acc;
    }
    __syncthreads();

    // GEMV2 for this block's 32 columns: c = g*32 + (t&31), 8 j-slices.
    const int c  = g * 32 + (t & 31);
    const int j0 = (t >> 5) * 32;
    float acc2 = 0.f;
    #pragma unroll 8
    for (int i = 0; i < 32; ++i) {
        const int j = j0 + i;
        acc2 += sv[j] * ow[j * 256 + c];   // sv broadcast-ish; ow 128B segments
    }
    red[t] = acc2;
    __syncthreads();
    if (t < 32) {
        float r = ob[g * 32 + t];
        #pragma unroll
        for (int s = 0; s < 8; ++s) r += red[t + 32 * s];
        o[b * 256 + g * 32 + t] = r;
    }
}

// Kernel 2: out[b,c,:,:] = img[b,c,:,:] + o[b,c]
// EXACT R0 configuration — the measured best (255.0 us total).
// Policy matrix (measured): NT/NT=255.0, NT/C=257.1, C/C=264.6, C/NT=266.1.
// NT loads avoid read-allocation into the poison-dirtied L3; NT stores
// matched/beat cached stores. One block per 16 KiB (b,c) plane,
// 8192 blocks x 256 threads, 4 float4 per thread.
__global__ __launch_bounds__(256) void residual_add_kernel(
    const float* __restrict__ img,
    const float* __restrict__ o,
    float* __restrict__ out)
{
    const int bc = blockIdx.x;        // 0..8191  (= b*256 + c)
    const int t  = threadIdx.x;
    const float ov = o[bc];
    const vfloat4* __restrict__ img4 = (const vfloat4*)(img + (size_t)bc * 4096);
    vfloat4* __restrict__ out4       = (vfloat4*)(out + (size_t)bc * 4096);
    #pragma unroll
    for (int i = 0; i < 4; ++i) {
        vfloat4 x = __builtin_nontemporal_load(img4 + t + 256 * i);
        x += ov;
        __builtin_nontemporal_store(x, out4 + t + 256 * i);
    }
}

extern "C" void kernel_launch(void* const* d_in, const int* in_sizes, int n_in,
                              void* d_out, int out_size, void* d_ws, size_t ws_size,
                              hipStream_t stream) {
    // Input order: img, act, gn_w, gn_b, ln_w, ln_b, qw, qb, kw, kb, vw, vb, ow, ob
    const float* img  = (const float*)d_in[0];
    const float* act  = (const float*)d_in[1];
    const float* ln_w = (const float*)d_in[4];
    const float* ln_b = (const float*)d_in[5];
    const float* vw   = (const float*)d_in[10];
    const float* vb   = (const float*)d_in[11];
    const float* ow   = (const float*)d_in[12];
    const float* ob   = (const float*)d_in[13];
    float* out = (float*)d_out;
    float* o   = (float*)d_ws;   // 32*256 floats = 32 KB scratch

    compute_o_kernel<<<256, 256, 0, stream>>>(act, ln_w, ln_b, vw, vb, ow, ob, o);
    residual_add_kernel<<<8192, 256, 0, stream>>>(img, o, out);
}